// Round 1
// baseline (508.411 us; speedup 1.0000x reference)
//
#include <hip/hip_runtime.h>
#include <hip/hip_bf16.h>

#define NN   8192
#define INCH 256
#define OUTC 64
#define LOG2E 1.44269504088896340736f

typedef __attribute__((ext_vector_type(8))) short bf16x8;
typedef __attribute__((ext_vector_type(4))) float f32x4;

static __device__ __forceinline__ unsigned short to_bf16u(float f) {
  // round-to-nearest-even bf16 truncation (finite inputs only)
  unsigned int u = __float_as_uint(f);
  unsigned int r = u + 0x7FFFu + ((u >> 16) & 1u);
  return (unsigned short)(r >> 16);
}

// K1: seq_fts = x @ W1^T (f32), f1 = seq_fts@a1, f2 = seq_fts@a2.
// grid 512, block 256. Each block: 16 rows. Thread (k=tid&63, ig=tid>>6) does 4 rows.
__global__ __launch_bounds__(256) void k1_seqfts(
    const float* __restrict__ x, const float* __restrict__ W1,
    const float* __restrict__ a1, const float* __restrict__ a2,
    float* __restrict__ sf, float* __restrict__ f1, float* __restrict__ f2) {
  __shared__ float xs[16 * INCH];
  const int tid = threadIdx.x;
  const int i0 = blockIdx.x * 16;
  const float4* __restrict__ xg = reinterpret_cast<const float4*>(x + (size_t)i0 * INCH);
  float4* xsv = reinterpret_cast<float4*>(xs);
  #pragma unroll
  for (int idx = tid; idx < 16 * (INCH / 4); idx += 256) xsv[idx] = xg[idx];
  __syncthreads();
  const int k = tid & 63;
  const int ig = tid >> 6;
  const float4* __restrict__ wv = reinterpret_cast<const float4*>(W1 + (size_t)k * INCH);
  const float4* xr0 = reinterpret_cast<const float4*>(xs + (ig * 4 + 0) * INCH);
  const float4* xr1 = reinterpret_cast<const float4*>(xs + (ig * 4 + 1) * INCH);
  const float4* xr2 = reinterpret_cast<const float4*>(xs + (ig * 4 + 2) * INCH);
  const float4* xr3 = reinterpret_cast<const float4*>(xs + (ig * 4 + 3) * INCH);
  float acc0 = 0.f, acc1 = 0.f, acc2 = 0.f, acc3 = 0.f;
  #pragma unroll 8
  for (int c4 = 0; c4 < INCH / 4; ++c4) {
    const float4 w = wv[c4];
    float4 v;
    v = xr0[c4];
    acc0 = fmaf(w.x, v.x, acc0); acc0 = fmaf(w.y, v.y, acc0);
    acc0 = fmaf(w.z, v.z, acc0); acc0 = fmaf(w.w, v.w, acc0);
    v = xr1[c4];
    acc1 = fmaf(w.x, v.x, acc1); acc1 = fmaf(w.y, v.y, acc1);
    acc1 = fmaf(w.z, v.z, acc1); acc1 = fmaf(w.w, v.w, acc1);
    v = xr2[c4];
    acc2 = fmaf(w.x, v.x, acc2); acc2 = fmaf(w.y, v.y, acc2);
    acc2 = fmaf(w.z, v.z, acc2); acc2 = fmaf(w.w, v.w, acc2);
    v = xr3[c4];
    acc3 = fmaf(w.x, v.x, acc3); acc3 = fmaf(w.y, v.y, acc3);
    acc3 = fmaf(w.z, v.z, acc3); acc3 = fmaf(w.w, v.w, acc3);
  }
  const float A1 = a1[k], A2 = a2[k];
  #pragma unroll
  for (int r = 0; r < 4; ++r) {
    const float sv = (r == 0) ? acc0 : (r == 1) ? acc1 : (r == 2) ? acc2 : acc3;
    const int i = i0 + ig * 4 + r;
    sf[(size_t)i * OUTC + k] = sv;
    float v1 = sv * A1, v2 = sv * A2;
    #pragma unroll
    for (int m = 32; m >= 1; m >>= 1) {
      v1 += __shfl_xor(v1, m, 64);
      v2 += __shfl_xor(v2, m, 64);
    }
    if (k == 0) { f1[i] = v1; f2[i] = v2; }
  }
}

// K2: partial column sums of exp(leakyrelu(f1[j]+f2[i]) + bias[i][j]).
// grid (8, 128), block 256. Block covers cols jb*1024..+1024 (4/thread), rows rc*64..+64.
__global__ __launch_bounds__(256) void k2_colsum(
    const float* __restrict__ bias, const float* __restrict__ f1,
    const float* __restrict__ f2, float* __restrict__ Sp) {
  const int j = blockIdx.x * 1024 + threadIdx.x * 4;
  const int ibase = blockIdx.y * 64;
  const float4 F1 = *reinterpret_cast<const float4*>(f1 + j);
  float s0 = 0.f, s1 = 0.f, s2 = 0.f, s3 = 0.f;
  #pragma unroll 4
  for (int ii = 0; ii < 64; ++ii) {
    const int i = ibase + ii;
    const float fi = f2[i];
    const float4 b = *reinterpret_cast<const float4*>(bias + (size_t)i * NN + j);
    float t;
    t = F1.x + fi; t = fmaxf(t, 0.01f * t); s0 += exp2f((t + b.x) * LOG2E);
    t = F1.y + fi; t = fmaxf(t, 0.01f * t); s1 += exp2f((t + b.y) * LOG2E);
    t = F1.z + fi; t = fmaxf(t, 0.01f * t); s2 += exp2f((t + b.z) * LOG2E);
    t = F1.w + fi; t = fmaxf(t, 0.01f * t); s3 += exp2f((t + b.w) * LOG2E);
  }
  *reinterpret_cast<float4*>(Sp + (size_t)blockIdx.y * NN + j) =
      make_float4(s0, s1, s2, s3);
}

// K2b: R[j] = 1 / sum_c Sp[c][j].  grid 128, block 64.
__global__ __launch_bounds__(64) void k2b_recip(
    const float* __restrict__ Sp, float* __restrict__ R) {
  const int j = blockIdx.x * 64 + threadIdx.x;
  float s = 0.f;
  #pragma unroll 8
  for (int c = 0; c < 128; ++c) s += Sp[(size_t)c * NN + j];
  R[j] = 1.0f / s;
}

// K2c: sT'[k][j] = bf16(sf[j][k] * R[j]).  grid 64, block 256 (128 j-rows per block).
__global__ __launch_bounds__(256) void k2c_transpose(
    const float* __restrict__ sf, const float* __restrict__ R,
    unsigned short* __restrict__ sT) {
  __shared__ float ls[128 * 65];
  __shared__ float Rl[128];
  const int tid = threadIdx.x;
  const int j0 = blockIdx.x * 128;
  const float4* __restrict__ sv = reinterpret_cast<const float4*>(sf + (size_t)j0 * OUTC);
  #pragma unroll
  for (int idx = tid; idx < 128 * 16; idx += 256) {
    const int row = idx >> 4, c4 = (idx & 15) * 4;
    const float4 v = sv[idx];
    float* d = ls + row * 65 + c4;
    d[0] = v.x; d[1] = v.y; d[2] = v.z; d[3] = v.w;
  }
  if (tid < 128) Rl[tid] = R[j0 + tid];
  __syncthreads();
  #pragma unroll
  for (int idx = tid; idx < OUTC * 128; idx += 256) {
    const int k = idx >> 7, jj = idx & 127;
    const float v = ls[jj * 65 + k] * Rl[jj];
    sT[(size_t)k * NN + j0 + jj] = to_bf16u(v);
  }
}

// K3: ret partials via swapped MFMA: D[k, i] += sT'[k, j] * P[i, j].
// grid (128 i-tiles, 8 j-splits), block 256 = 4 waves, wave owns 16 i-rows.
__global__ __launch_bounds__(256, 4) void k3_pv(
    const float* __restrict__ bias, const float* __restrict__ f1,
    const float* __restrict__ f2, const unsigned short* __restrict__ sT,
    float* __restrict__ retp) {
  const int tid = threadIdx.x;
  const int w = tid >> 6;
  const int l = tid & 63;
  const int lr = l & 15;   // i-col within wave tile; also sT row within k-tile
  const int lg = l >> 4;   // 0..3 -> j sub-offset *8
  const int i = blockIdx.x * 64 + w * 16 + lr;
  const int jbase = blockIdx.y * 1024 + lg * 8;
  const float fi = f2[i];
  f32x4 acc0 = {0.f, 0.f, 0.f, 0.f}, acc1 = {0.f, 0.f, 0.f, 0.f};
  f32x4 acc2 = {0.f, 0.f, 0.f, 0.f}, acc3 = {0.f, 0.f, 0.f, 0.f};
  const float* __restrict__ brow = bias + (size_t)i * NN;
  const unsigned short* __restrict__ st0 = sT + (size_t)(0 * 16 + lr) * NN;
  const unsigned short* __restrict__ st1 = sT + (size_t)(1 * 16 + lr) * NN;
  const unsigned short* __restrict__ st2 = sT + (size_t)(2 * 16 + lr) * NN;
  const unsigned short* __restrict__ st3 = sT + (size_t)(3 * 16 + lr) * NN;
  #pragma unroll 2
  for (int s = 0; s < 32; ++s) {
    const int j = jbase + s * 32;
    const float4 b0 = *reinterpret_cast<const float4*>(brow + j);
    const float4 b1 = *reinterpret_cast<const float4*>(brow + j + 4);
    const float4 fa = *reinterpret_cast<const float4*>(f1 + j);
    const float4 fb = *reinterpret_cast<const float4*>(f1 + j + 4);
    float t, e0, e1, e2, e3, e4, e5, e6, e7;
    t = fa.x + fi; t = fmaxf(t, 0.01f * t); e0 = exp2f((t + b0.x) * LOG2E);
    t = fa.y + fi; t = fmaxf(t, 0.01f * t); e1 = exp2f((t + b0.y) * LOG2E);
    t = fa.z + fi; t = fmaxf(t, 0.01f * t); e2 = exp2f((t + b0.z) * LOG2E);
    t = fa.w + fi; t = fmaxf(t, 0.01f * t); e3 = exp2f((t + b0.w) * LOG2E);
    t = fb.x + fi; t = fmaxf(t, 0.01f * t); e4 = exp2f((t + b1.x) * LOG2E);
    t = fb.y + fi; t = fmaxf(t, 0.01f * t); e5 = exp2f((t + b1.y) * LOG2E);
    t = fb.z + fi; t = fmaxf(t, 0.01f * t); e6 = exp2f((t + b1.z) * LOG2E);
    t = fb.w + fi; t = fmaxf(t, 0.01f * t); e7 = exp2f((t + b1.w) * LOG2E);
    bf16x8 B;
    B[0] = (short)to_bf16u(e0); B[1] = (short)to_bf16u(e1);
    B[2] = (short)to_bf16u(e2); B[3] = (short)to_bf16u(e3);
    B[4] = (short)to_bf16u(e4); B[5] = (short)to_bf16u(e5);
    B[6] = (short)to_bf16u(e6); B[7] = (short)to_bf16u(e7);
    const bf16x8 A0 = *reinterpret_cast<const bf16x8*>(st0 + j);
    const bf16x8 A1 = *reinterpret_cast<const bf16x8*>(st1 + j);
    const bf16x8 A2 = *reinterpret_cast<const bf16x8*>(st2 + j);
    const bf16x8 A3 = *reinterpret_cast<const bf16x8*>(st3 + j);
    acc0 = __builtin_amdgcn_mfma_f32_16x16x32_bf16(A0, B, acc0, 0, 0, 0);
    acc1 = __builtin_amdgcn_mfma_f32_16x16x32_bf16(A1, B, acc1, 0, 0, 0);
    acc2 = __builtin_amdgcn_mfma_f32_16x16x32_bf16(A2, B, acc2, 0, 0, 0);
    acc3 = __builtin_amdgcn_mfma_f32_16x16x32_bf16(A3, B, acc3, 0, 0, 0);
  }
  float* __restrict__ outp =
      retp + (size_t)blockIdx.y * (NN * OUTC) + (size_t)i * OUTC;
  #pragma unroll
  for (int q = 0; q < 4; ++q) {
    outp[ 0 + lg * 4 + q] = acc0[q];
    outp[16 + lg * 4 + q] = acc1[q];
    outp[32 + lg * 4 + q] = acc2[q];
    outp[48 + lg * 4 + q] = acc3[q];
  }
}

// K3b: out = elu(sum of 8 partials).  grid 512, block 256 (float4/thread).
__global__ __launch_bounds__(256) void k3b_combine(
    const float* __restrict__ retp, float* __restrict__ out) {
  const int idx = (blockIdx.x * 256 + threadIdx.x) * 4;
  float4 s = *reinterpret_cast<const float4*>(retp + idx);
  #pragma unroll
  for (int p = 1; p < 8; ++p) {
    const float4 v =
        *reinterpret_cast<const float4*>(retp + (size_t)p * (NN * OUTC) + idx);
    s.x += v.x; s.y += v.y; s.z += v.z; s.w += v.w;
  }
  s.x = (s.x > 0.f) ? s.x : expm1f(s.x);
  s.y = (s.y > 0.f) ? s.y : expm1f(s.y);
  s.z = (s.z > 0.f) ? s.z : expm1f(s.z);
  s.w = (s.w > 0.f) ? s.w : expm1f(s.w);
  *reinterpret_cast<float4*>(out + idx) = s;
}

extern "C" void kernel_launch(void* const* d_in, const int* in_sizes, int n_in,
                              void* d_out, int out_size, void* d_ws, size_t ws_size,
                              hipStream_t stream) {
  const float* x    = (const float*)d_in[0];
  const float* bias = (const float*)d_in[1];
  const float* W1   = (const float*)d_in[2];
  const float* a1   = (const float*)d_in[3];
  const float* a2   = (const float*)d_in[4];
  float* out = (float*)d_out;

  // workspace layout (float offsets)
  float* wsf = (float*)d_ws;
  float* f1   = wsf;                         // 8192
  float* f2   = wsf + 8192;                  // 8192
  float* R    = wsf + 16384;                 // 8192
  float* sf   = wsf + 24576;                 // 8192*64 = 524288
  float* Sp   = wsf + 24576 + 524288;        // 128*8192 = 1048576
  float* retp = wsf + 1597440;               // 8*524288 = 4194304
  unsigned short* sT = (unsigned short*)(wsf + 1597440 + 4194304);  // 64*8192 bf16

  k1_seqfts<<<512, 256, 0, stream>>>(x, W1, a1, a2, sf, f1, f2);
  k2_colsum<<<dim3(8, 128), 256, 0, stream>>>(bias, f1, f2, Sp);
  k2b_recip<<<128, 64, 0, stream>>>(Sp, R);
  k2c_transpose<<<64, 256, 0, stream>>>(sf, R, sT);
  k3_pv<<<dim3(128, 8), 256, 0, stream>>>(bias, f1, f2, sT, retp);
  k3b_combine<<<512, 256, 0, stream>>>(retp, out);
}